// Round 1
// baseline (58.391 us; speedup 1.0000x reference)
//
#include <hip/hip_runtime.h>
#include <math.h>

#define PI_F 3.14159265358979323846f

// cos/sin table for the 84 static weight angles, filled by qa_setup each call.
// Layout (float pairs: cos(t/2), sin(t/2)):
//   [0..47]    wq_rot (24 pairs)
//   [48..55]   wq_crx (4 pairs)
//   [56..103]  wk_rot (24 pairs)
//   [104..111] wk_crx (4 pairs)
//   [112..159] wv_rot (24 pairs)
//   [160..167] wv_crx (4 pairs)
__device__ float g_cs[168];

__global__ void qa_setup(const float* wq_rot, const float* wq_crx,
                         const float* wk_rot, const float* wk_crx,
                         const float* wv_rot, const float* wv_crx) {
    int t = threadIdx.x;
    float ang; int off;
    if (t < 24)      { ang = wq_rot[t];      off = 0   + 2*t;      }
    else if (t < 28) { ang = wq_crx[t-24];   off = 48  + 2*(t-24); }
    else if (t < 52) { ang = wk_rot[t-28];   off = 56  + 2*(t-28); }
    else if (t < 56) { ang = wk_crx[t-52];   off = 104 + 2*(t-52); }
    else if (t < 80) { ang = wv_rot[t-56];   off = 112 + 2*(t-56); }
    else if (t < 84) { ang = wv_crx[t-80];   off = 160 + 2*(t-80); }
    else return;
    float s, c;
    sincosf(ang * 0.5f, &s, &c);
    g_cs[off] = c; g_cs[off+1] = s;
}

// ---------------------------------------------------------------------------
// State layout: amplitude a (8 bits) = r*16 + g, r = register idx (wires 0-3,
// wire w -> r bit (3-w) -> mask 8>>w), g = lane-in-group (wires 4-7,
// wire w -> g bit (7-w) -> mask 8>>(w-4)). Complex split into sr[]/si[].
// All register loops fully unrolled with compile-time masks (no scratch).
// ---------------------------------------------------------------------------

// RZ on register wire: diag(e^{-it/2}, e^{+it/2})
template<int M>
__device__ __forceinline__ void rz_reg(float sr[16], float si[16], float c, float s) {
#pragma unroll
    for (int r = 0; r < 16; ++r) {
        float d = (r & M) ? s : -s;
        float re = sr[r], im = si[r];
        sr[r] = c*re - d*im;
        si[r] = c*im + d*re;
    }
}

// RX on register wire: [[c, -is],[-is, c]]
template<int M>
__device__ __forceinline__ void rx_reg(float sr[16], float si[16], float c, float s) {
#pragma unroll
    for (int r0 = 0; r0 < 16; ++r0) {
        if (r0 & M) continue;
        int r1 = r0 | M;
        float a0r = sr[r0], a0i = si[r0], a1r = sr[r1], a1i = si[r1];
        sr[r0] = fmaf(s, a1i, c*a0r);
        si[r0] = fmaf(-s, a1r, c*a0i);
        sr[r1] = fmaf(s, a0i, c*a1r);
        si[r1] = fmaf(-s, a0r, c*a1i);
    }
}

template<int CM, int TM>
__device__ __forceinline__ void crx_reg(float sr[16], float si[16], float c, float s) {
#pragma unroll
    for (int r0 = 0; r0 < 16; ++r0) {
        if ((r0 & CM) == 0 || (r0 & TM)) continue;
        int r1 = r0 | TM;
        float a0r = sr[r0], a0i = si[r0], a1r = sr[r1], a1i = si[r1];
        sr[r0] = fmaf(s, a1i, c*a0r);
        si[r0] = fmaf(-s, a1r, c*a0i);
        sr[r1] = fmaf(s, a0i, c*a1r);
        si[r1] = fmaf(-s, a0r, c*a1i);
    }
}

template<int CM, int TM>
__device__ __forceinline__ void cnot_reg(float sr[16], float si[16]) {
#pragma unroll
    for (int r0 = 0; r0 < 16; ++r0) {
        if ((r0 & CM) == 0 || (r0 & TM)) continue;
        int r1 = r0 | TM;
        float t;
        t = sr[r0]; sr[r0] = sr[r1]; sr[r1] = t;
        t = si[r0]; si[r0] = si[r1]; si[r1] = t;
    }
}

// ---- lane-wire (wires 4-7) variants --------------------------------------

template<int LM>
__device__ __forceinline__ void rz_lane(float sr[16], float si[16], float c, float s, int g) {
    float d = (g & LM) ? s : -s;
#pragma unroll
    for (int r = 0; r < 16; ++r) {
        float re = sr[r], im = si[r];
        sr[r] = c*re - d*im;
        si[r] = c*im + d*re;
    }
}

template<int LM>
__device__ __forceinline__ void rx_lane(float sr[16], float si[16], float c, float s) {
#pragma unroll
    for (int r = 0; r < 16; ++r) {
        float pr = __shfl_xor(sr[r], LM);
        float pi = __shfl_xor(si[r], LM);
        // new = c*mine - i*s*partner  (diagonal symmetric, bit-independent)
        sr[r] = fmaf(s, pi, c*sr[r]);
        si[r] = fmaf(-s, pr, c*si[r]);
    }
}

template<int CLM, int TLM>
__device__ __forceinline__ void crx_lane(float sr[16], float si[16], float c, float s, int g) {
    bool ctl = (g & CLM) != 0;
#pragma unroll
    for (int r = 0; r < 16; ++r) {
        float pr = __shfl_xor(sr[r], TLM);
        float pi = __shfl_xor(si[r], TLM);
        float nr = fmaf(s, pi, c*sr[r]);
        float ni = fmaf(-s, pr, c*si[r]);
        sr[r] = ctl ? nr : sr[r];
        si[r] = ctl ? ni : si[r];
    }
}

template<int CLM, int TLM>
__device__ __forceinline__ void cnot_lane(float sr[16], float si[16], int g) {
    bool ctl = (g & CLM) != 0;
#pragma unroll
    for (int r = 0; r < 16; ++r) {
        float pr = __shfl_xor(sr[r], TLM);
        float pi = __shfl_xor(si[r], TLM);
        sr[r] = ctl ? pr : sr[r];
        si[r] = ctl ? pi : si[r];
    }
}

// CNOT control on register wire (CM), target on lane wire (TLM)
template<int CM, int TLM>
__device__ __forceinline__ void cnot_reg_lane(float sr[16], float si[16]) {
#pragma unroll
    for (int r = 0; r < 16; ++r) {
        if ((r & CM) == 0) continue;
        sr[r] = __shfl_xor(sr[r], TLM);
        si[r] = __shfl_xor(si[r], TLM);
    }
}

// CNOT control on lane wire (CLM), target on register wire (TM)
template<int CLM, int TM>
__device__ __forceinline__ void cnot_lane_reg(float sr[16], float si[16], int g) {
    bool ctl = (g & CLM) != 0;
#pragma unroll
    for (int r0 = 0; r0 < 16; ++r0) {
        if (r0 & TM) continue;
        int r1 = r0 | TM;
        float a = sr[r0], b = sr[r1];
        sr[r0] = ctl ? b : a; sr[r1] = ctl ? a : b;
        float ai = si[r0], bi = si[r1];
        si[r0] = ctl ? bi : ai; si[r1] = ctl ? ai : bi;
    }
}

// init_qkv with all 4 wires on register bits (offset 0; also value circuit)
__device__ __forceinline__ void init_qkv_reg(float sr[16], float si[16],
                                             const float* rc, const float* cc) {
    rz_reg<8>(sr,si, rc[0],  rc[1]);
    rx_reg<8>(sr,si, rc[2],  rc[3]);
    rz_reg<8>(sr,si, rc[4],  rc[5]);
    rz_reg<4>(sr,si, rc[6],  rc[7]);
    rx_reg<4>(sr,si, rc[8],  rc[9]);
    rz_reg<4>(sr,si, rc[10], rc[11]);
    rz_reg<2>(sr,si, rc[12], rc[13]);
    rx_reg<2>(sr,si, rc[14], rc[15]);
    rz_reg<2>(sr,si, rc[16], rc[17]);
    rz_reg<1>(sr,si, rc[18], rc[19]);
    rx_reg<1>(sr,si, rc[20], rc[21]);
    rz_reg<1>(sr,si, rc[22], rc[23]);
    crx_reg<8,4>(sr,si, cc[0], cc[1]);
    crx_reg<4,2>(sr,si, cc[2], cc[3]);
    crx_reg<2,1>(sr,si, cc[4], cc[5]);
    crx_reg<1,8>(sr,si, cc[6], cc[7]);
    cnot_reg<8,4>(sr,si);
    cnot_reg<4,2>(sr,si);
    cnot_reg<2,1>(sr,si);
    cnot_reg<1,8>(sr,si);
    cnot_reg<8,1>(sr,si);
    cnot_reg<4,8>(sr,si);
    cnot_reg<2,4>(sr,si);
    cnot_reg<1,2>(sr,si);
    rz_reg<8>(sr,si, rc[24], rc[25]);
    rx_reg<8>(sr,si, rc[26], rc[27]);
    rz_reg<8>(sr,si, rc[28], rc[29]);
    rz_reg<4>(sr,si, rc[30], rc[31]);
    rx_reg<4>(sr,si, rc[32], rc[33]);
    rz_reg<4>(sr,si, rc[34], rc[35]);
    rz_reg<2>(sr,si, rc[36], rc[37]);
    rx_reg<2>(sr,si, rc[38], rc[39]);
    rz_reg<2>(sr,si, rc[40], rc[41]);
    rz_reg<1>(sr,si, rc[42], rc[43]);
    rx_reg<1>(sr,si, rc[44], rc[45]);
    rz_reg<1>(sr,si, rc[46], rc[47]);
}

// init_qkv with all 4 wires on lane bits (offset 4, K side)
__device__ __forceinline__ void init_qkv_lane(float sr[16], float si[16],
                                              const float* rc, const float* cc, int g) {
    rz_lane<8>(sr,si, rc[0],  rc[1],  g);
    rx_lane<8>(sr,si, rc[2],  rc[3]);
    rz_lane<8>(sr,si, rc[4],  rc[5],  g);
    rz_lane<4>(sr,si, rc[6],  rc[7],  g);
    rx_lane<4>(sr,si, rc[8],  rc[9]);
    rz_lane<4>(sr,si, rc[10], rc[11], g);
    rz_lane<2>(sr,si, rc[12], rc[13], g);
    rx_lane<2>(sr,si, rc[14], rc[15]);
    rz_lane<2>(sr,si, rc[16], rc[17], g);
    rz_lane<1>(sr,si, rc[18], rc[19], g);
    rx_lane<1>(sr,si, rc[20], rc[21]);
    rz_lane<1>(sr,si, rc[22], rc[23], g);
    crx_lane<8,4>(sr,si, cc[0], cc[1], g);
    crx_lane<4,2>(sr,si, cc[2], cc[3], g);
    crx_lane<2,1>(sr,si, cc[4], cc[5], g);
    crx_lane<1,8>(sr,si, cc[6], cc[7], g);
    cnot_lane<8,4>(sr,si,g);
    cnot_lane<4,2>(sr,si,g);
    cnot_lane<2,1>(sr,si,g);
    cnot_lane<1,8>(sr,si,g);
    cnot_lane<8,1>(sr,si,g);
    cnot_lane<4,8>(sr,si,g);
    cnot_lane<2,4>(sr,si,g);
    cnot_lane<1,2>(sr,si,g);
    rz_lane<8>(sr,si, rc[24], rc[25], g);
    rx_lane<8>(sr,si, rc[26], rc[27]);
    rz_lane<8>(sr,si, rc[28], rc[29], g);
    rz_lane<4>(sr,si, rc[30], rc[31], g);
    rx_lane<4>(sr,si, rc[32], rc[33]);
    rz_lane<4>(sr,si, rc[34], rc[35], g);
    rz_lane<2>(sr,si, rc[36], rc[37], g);
    rx_lane<2>(sr,si, rc[38], rc[39]);
    rz_lane<2>(sr,si, rc[40], rc[41], g);
    rz_lane<1>(sr,si, rc[42], rc[43], g);
    rx_lane<1>(sr,si, rc[44], rc[45]);
    rz_lane<1>(sr,si, rc[46], rc[47], g);
}

__global__ __launch_bounds__(256) void qa_main(
        const float* __restrict__ x1, const float* __restrict__ x2,
        const float* __restrict__ W, const float* __restrict__ b,
        float* __restrict__ out, int B) {
    int tid = blockIdx.x * blockDim.x + threadIdx.x;
    int e = tid >> 4;          // batch element (16 lanes per element)
    int g = tid & 15;          // lane-in-group = wires 4-7 bits
    if (e >= B) return;

    // ---- pre-net: x1p/x2p = row @ W^T + b (coalesced, split over 16 lanes)
    float acc1[4] = {0,0,0,0}, acc2[4] = {0,0,0,0};
    const float* x1row = x1 + (size_t)e * 96;
    const float* x2row = x2 + (size_t)e * 96;
#pragma unroll
    for (int k = 0; k < 6; ++k) {
        int i = g + 16*k;
        float v1 = x1row[i], v2 = x2row[i];
#pragma unroll
        for (int d = 0; d < 4; ++d) {
            float w = W[d*96 + i];
            acc1[d] = fmaf(v1, w, acc1[d]);
            acc2[d] = fmaf(v2, w, acc2[d]);
        }
    }
#pragma unroll
    for (int m = 1; m < 16; m <<= 1) {
#pragma unroll
        for (int d = 0; d < 4; ++d) {
            acc1[d] += __shfl_xor(acc1[d], m);
            acc2[d] += __shfl_xor(acc2[d], m);
        }
    }
    float cq[4], sq[4], ck[4], sk[4];
#pragma unroll
    for (int d = 0; d < 4; ++d) {
        float x1p = acc1[d] + b[d];
        float x2p = acc2[d] + b[d];
        sincosf(0.5f * x1p, &sq[d], &cq[d]);
        sincosf(0.5f * x2p, &sk[d], &ck[d]);
    }

    // ---- 8-qubit score circuit
    float sr[16], si[16];
#pragma unroll
    for (int r = 0; r < 16; ++r) { sr[r] = 0.f; si[r] = 0.f; }
    sr[0] = (g == 0) ? 1.f : 0.f;

    // AngleEmbedding RX(x1p) on wires 0-3 (register wires)
    rx_reg<8>(sr,si,cq[0],sq[0]);
    rx_reg<4>(sr,si,cq[1],sq[1]);
    rx_reg<2>(sr,si,cq[2],sq[2]);
    rx_reg<1>(sr,si,cq[3],sq[3]);
    init_qkv_reg(sr,si, g_cs + 0, g_cs + 48);           // Q on wires 0-3
    // AngleEmbedding RX(x2p) on wires 0-3
    rx_reg<8>(sr,si,ck[0],sk[0]);
    rx_reg<4>(sr,si,ck[1],sk[1]);
    rx_reg<2>(sr,si,ck[2],sk[2]);
    rx_reg<1>(sr,si,ck[3],sk[3]);
    init_qkv_lane(sr,si, g_cs + 56, g_cs + 104, g);     // K on wires 4-7
    // entangling CNOTs (0,4),(4,0),(1,5),(5,1),(2,6),(6,2),(3,7),(7,3)
    cnot_reg_lane<8,8>(sr,si);
    cnot_lane_reg<8,8>(sr,si,g);
    cnot_reg_lane<4,4>(sr,si);
    cnot_lane_reg<4,4>(sr,si,g);
    cnot_reg_lane<2,2>(sr,si);
    cnot_lane_reg<2,2>(sr,si,g);
    cnot_reg_lane<1,1>(sr,si);
    cnot_lane_reg<1,1>(sr,si,g);

    // ---- measurements on wires 1,2,3 (reg masks 4,2,1) and 4 (lane mask 8)
    float z[4] = {0,0,0,0}, x[4] = {0,0,0,0};
#pragma unroll
    for (int r = 0; r < 16; ++r) {
        float p = sr[r]*sr[r] + si[r]*si[r];
        z[0] += (r & 4) ? -p : p;
        z[1] += (r & 2) ? -p : p;
        z[2] += (r & 1) ? -p : p;
        z[3] += p;
        x[0] += sr[r]*sr[r^4] + si[r]*si[r^4];
        x[1] += sr[r]*sr[r^2] + si[r]*si[r^2];
        x[2] += sr[r]*sr[r^1] + si[r]*si[r^1];
        float pr = __shfl_xor(sr[r], 8);
        float pi = __shfl_xor(si[r], 8);
        x[3] += sr[r]*pr + si[r]*pi;
    }
    z[3] = (g & 8) ? -z[3] : z[3];
#pragma unroll
    for (int m = 1; m < 16; m <<= 1) {
#pragma unroll
        for (int d = 0; d < 4; ++d) {
            z[d] += __shfl_xor(z[d], m);
            x[d] += __shfl_xor(x[d], m);
        }
    }

    // ---- mag -> tanh -> value embedding angles
    float cv[4], sv[4];
#pragma unroll
    for (int d = 0; d < 4; ++d) {
        float mag = sqrtf(z[d]*z[d] + x[d]*x[d]);
        float ang = tanhf(mag) * PI_F;
        sincosf(0.5f * ang, &sv[d], &cv[d]);
    }

    // ---- 4-qubit value circuit (full 16-amp state per lane, redundant)
#pragma unroll
    for (int r = 0; r < 16; ++r) { sr[r] = 0.f; si[r] = 0.f; }
    sr[0] = 1.f;
    rx_reg<8>(sr,si,ck[0],sk[0]);   // RX(xv) with xv = x2p
    rx_reg<4>(sr,si,ck[1],sk[1]);
    rx_reg<2>(sr,si,ck[2],sk[2]);
    rx_reg<1>(sr,si,ck[3],sk[3]);
    init_qkv_reg(sr,si, g_cs + 112, g_cs + 160);        // V
    rx_reg<8>(sr,si,cv[0],sv[0]);   // RX(tanh(mag)*pi)
    rx_reg<4>(sr,si,cv[1],sv[1]);
    rx_reg<2>(sr,si,cv[2],sv[2]);
    rx_reg<1>(sr,si,cv[3],sv[3]);
    cnot_reg<8,4>(sr,si);
    cnot_reg<4,2>(sr,si);
    cnot_reg<2,1>(sr,si);
    cnot_reg<1,8>(sr,si);

    float zo0=0,zo1=0,zo2=0,zo3=0, xo0=0,xo1=0,xo2=0,xo3=0;
#pragma unroll
    for (int r = 0; r < 16; ++r) {
        float p = sr[r]*sr[r] + si[r]*si[r];
        zo0 += (r & 8) ? -p : p;
        zo1 += (r & 4) ? -p : p;
        zo2 += (r & 2) ? -p : p;
        zo3 += (r & 1) ? -p : p;
        xo0 += sr[r]*sr[r^8] + si[r]*si[r^8];
        xo1 += sr[r]*sr[r^4] + si[r]*si[r^4];
        xo2 += sr[r]*sr[r^2] + si[r]*si[r^2];
        xo3 += sr[r]*sr[r^1] + si[r]*si[r^1];
    }

    if (g == 0) {
        float* o = out + (size_t)e * 8;
        o[0] = zo0; o[1] = zo1; o[2] = zo2; o[3] = zo3;
        o[4] = xo0; o[5] = xo1; o[6] = xo2; o[7] = xo3;
    }
}

extern "C" void kernel_launch(void* const* d_in, const int* in_sizes, int n_in,
                              void* d_out, int out_size, void* d_ws, size_t ws_size,
                              hipStream_t stream) {
    const float* x1     = (const float*)d_in[0];
    const float* x2     = (const float*)d_in[1];
    const float* W      = (const float*)d_in[2];
    const float* b      = (const float*)d_in[3];
    const float* wq_rot = (const float*)d_in[4];
    const float* wq_crx = (const float*)d_in[5];
    const float* wk_rot = (const float*)d_in[6];
    const float* wk_crx = (const float*)d_in[7];
    const float* wv_rot = (const float*)d_in[8];
    const float* wv_crx = (const float*)d_in[9];
    float* out = (float*)d_out;
    int B = in_sizes[0] / 96;

    qa_setup<<<1, 128, 0, stream>>>(wq_rot, wq_crx, wk_rot, wk_crx, wv_rot, wv_crx);

    int threads = B * 16;
    qa_main<<<(threads + 255) / 256, 256, 0, stream>>>(x1, x2, W, b, out, B);
}

// Round 4
// 13.938 us; speedup vs baseline: 4.1894x; 4.1894x over previous
//
#include <hip/hip_runtime.h>
#include <math.h>

#define PI_F 3.14159265358979323846f

// ---------------------------------------------------------------------------
// Fused single-kernel quantum attention.
// 4 lanes per batch element. 4-qubit state (16 amps) split:
//   wires 0,1 -> lane-quad bits (q = lane&3: bit1 = wire0, bit0 = wire1)
//   wires 2,3 -> register index  (r: bit1 = wire2, bit0 = wire3)
// Each lane holds sr[4]/si[4] (4 complex amps). All cross-lane traffic is
// __shfl_xor with mask 1/2 (intra-quad) or width-4 broadcasts.
// No module-scope device state; per-block LDS table; one __syncthreads.
// ---------------------------------------------------------------------------

__device__ __forceinline__ float qred(float v) {
    v += __shfl_xor(v, 1);
    v += __shfl_xor(v, 2);
    return v;
}

// ---- register-wire gates (wire2 -> M=2, wire3 -> M=1) ----------------------

template<int M>
__device__ __forceinline__ void rz_reg(float sr[4], float si[4], float c, float s) {
#pragma unroll
    for (int r = 0; r < 4; ++r) {
        float d = (r & M) ? s : -s;
        float re = sr[r], im = si[r];
        sr[r] = c*re - d*im;
        si[r] = c*im + d*re;
    }
}

template<int M>
__device__ __forceinline__ void rx_reg(float sr[4], float si[4], float c, float s) {
#pragma unroll
    for (int r0 = 0; r0 < 4; ++r0) {
        if (r0 & M) continue;
        int r1 = r0 | M;
        float a0r = sr[r0], a0i = si[r0], a1r = sr[r1], a1i = si[r1];
        sr[r0] = fmaf(s, a1i, c*a0r);
        si[r0] = fmaf(-s, a1r, c*a0i);
        sr[r1] = fmaf(s, a0i, c*a1r);
        si[r1] = fmaf(-s, a0r, c*a1i);
    }
}

template<int CM, int TM>
__device__ __forceinline__ void crx_rr(float sr[4], float si[4], float c, float s) {
#pragma unroll
    for (int r0 = 0; r0 < 4; ++r0) {
        if ((r0 & CM) == 0 || (r0 & TM)) continue;
        int r1 = r0 | TM;
        float a0r = sr[r0], a0i = si[r0], a1r = sr[r1], a1i = si[r1];
        sr[r0] = fmaf(s, a1i, c*a0r);
        si[r0] = fmaf(-s, a1r, c*a0i);
        sr[r1] = fmaf(s, a0i, c*a1r);
        si[r1] = fmaf(-s, a0r, c*a1i);
    }
}

template<int CM, int TM>
__device__ __forceinline__ void cnot_rr(float sr[4], float si[4]) {
#pragma unroll
    for (int r0 = 0; r0 < 4; ++r0) {
        if ((r0 & CM) == 0 || (r0 & TM)) continue;
        int r1 = r0 | TM;
        float t;
        t = sr[r0]; sr[r0] = sr[r1]; sr[r1] = t;
        t = si[r0]; si[r0] = si[r1]; si[r1] = t;
    }
}

// ---- lane-wire gates (wire0 -> L=2, wire1 -> L=1) ---------------------------

template<int L>
__device__ __forceinline__ void rz_lane(float sr[4], float si[4], float c, float s, int q) {
    float d = (q & L) ? s : -s;
#pragma unroll
    for (int r = 0; r < 4; ++r) {
        float re = sr[r], im = si[r];
        sr[r] = c*re - d*im;
        si[r] = c*im + d*re;
    }
}

template<int L>
__device__ __forceinline__ void rx_lane(float sr[4], float si[4], float c, float s) {
#pragma unroll
    for (int r = 0; r < 4; ++r) {
        float pr = __shfl_xor(sr[r], L);
        float pi = __shfl_xor(si[r], L);
        sr[r] = fmaf(s, pi, c*sr[r]);
        si[r] = fmaf(-s, pr, c*si[r]);
    }
}

template<int CL, int TL>
__device__ __forceinline__ void crx_ll(float sr[4], float si[4], float c, float s, int q) {
    bool ctl = (q & CL) != 0;
#pragma unroll
    for (int r = 0; r < 4; ++r) {
        float pr = __shfl_xor(sr[r], TL);
        float pi = __shfl_xor(si[r], TL);
        float nr = fmaf(s, pi, c*sr[r]);
        float ni = fmaf(-s, pr, c*si[r]);
        sr[r] = ctl ? nr : sr[r];
        si[r] = ctl ? ni : si[r];
    }
}

template<int CL, int TM>
__device__ __forceinline__ void crx_lr(float sr[4], float si[4], float c, float s, int q) {
    bool ctl = (q & CL) != 0;
#pragma unroll
    for (int r0 = 0; r0 < 4; ++r0) {
        if (r0 & TM) continue;
        int r1 = r0 | TM;
        float a0r = sr[r0], a0i = si[r0], a1r = sr[r1], a1i = si[r1];
        float n0r = fmaf(s, a1i, c*a0r), n0i = fmaf(-s, a1r, c*a0i);
        float n1r = fmaf(s, a0i, c*a1r), n1i = fmaf(-s, a0r, c*a1i);
        sr[r0] = ctl ? n0r : a0r;  si[r0] = ctl ? n0i : a0i;
        sr[r1] = ctl ? n1r : a1r;  si[r1] = ctl ? n1i : a1i;
    }
}

template<int CM, int TL>
__device__ __forceinline__ void crx_rl(float sr[4], float si[4], float c, float s) {
#pragma unroll
    for (int r = 0; r < 4; ++r) {
        if (!(r & CM)) continue;
        float pr = __shfl_xor(sr[r], TL);
        float pi = __shfl_xor(si[r], TL);
        sr[r] = fmaf(s, pi, c*sr[r]);
        si[r] = fmaf(-s, pr, c*si[r]);
    }
}

template<int CL, int TL>
__device__ __forceinline__ void cnot_ll(float sr[4], float si[4], int q) {
    bool ctl = (q & CL) != 0;
#pragma unroll
    for (int r = 0; r < 4; ++r) {
        float pr = __shfl_xor(sr[r], TL);
        float pi = __shfl_xor(si[r], TL);
        sr[r] = ctl ? pr : sr[r];
        si[r] = ctl ? pi : si[r];
    }
}

template<int CL, int TM>
__device__ __forceinline__ void cnot_lr(float sr[4], float si[4], int q) {
    bool ctl = (q & CL) != 0;
#pragma unroll
    for (int r0 = 0; r0 < 4; ++r0) {
        if (r0 & TM) continue;
        int r1 = r0 | TM;
        float a = sr[r0], b2 = sr[r1];
        sr[r0] = ctl ? b2 : a;  sr[r1] = ctl ? a : b2;
        float ai = si[r0], bi = si[r1];
        si[r0] = ctl ? bi : ai; si[r1] = ctl ? ai : bi;
    }
}

template<int CM, int TL>
__device__ __forceinline__ void cnot_rl(float sr[4], float si[4]) {
#pragma unroll
    for (int r = 0; r < 4; ++r) {
        if (!(r & CM)) continue;
        sr[r] = __shfl_xor(sr[r], TL);
        si[r] = __shfl_xor(si[r], TL);
    }
}

// ---- full init_qkv block on wires 0..3 (lane2, lane1, reg2, reg1) -----------
__device__ __forceinline__ void init_qkv4(float sr[4], float si[4],
        const float2* rc, const float2* cc, int q) {
    float2 t;
    // ZXZ layer 1
    t = rc[0];  rz_lane<2>(sr,si,t.x,t.y,q);
    t = rc[1];  rx_lane<2>(sr,si,t.x,t.y);
    t = rc[2];  rz_lane<2>(sr,si,t.x,t.y,q);
    t = rc[3];  rz_lane<1>(sr,si,t.x,t.y,q);
    t = rc[4];  rx_lane<1>(sr,si,t.x,t.y);
    t = rc[5];  rz_lane<1>(sr,si,t.x,t.y,q);
    t = rc[6];  rz_reg<2>(sr,si,t.x,t.y);
    t = rc[7];  rx_reg<2>(sr,si,t.x,t.y);
    t = rc[8];  rz_reg<2>(sr,si,t.x,t.y);
    t = rc[9];  rz_reg<1>(sr,si,t.x,t.y);
    t = rc[10]; rx_reg<1>(sr,si,t.x,t.y);
    t = rc[11]; rz_reg<1>(sr,si,t.x,t.y);
    // CRX ring (0,1),(1,2),(2,3),(3,0)
    t = cc[0];  crx_ll<2,1>(sr,si,t.x,t.y,q);
    t = cc[1];  crx_lr<1,2>(sr,si,t.x,t.y,q);
    t = cc[2];  crx_rr<2,1>(sr,si,t.x,t.y);
    t = cc[3];  crx_rl<1,2>(sr,si,t.x,t.y);
    // CNOTs (0,1),(1,2),(2,3),(3,0),(0,3),(1,0),(2,1),(3,2)
    cnot_ll<2,1>(sr,si,q);
    cnot_lr<1,2>(sr,si,q);
    cnot_rr<2,1>(sr,si);
    cnot_rl<1,2>(sr,si);
    cnot_lr<2,1>(sr,si,q);
    cnot_ll<1,2>(sr,si,q);
    cnot_rl<2,1>(sr,si);
    cnot_rr<1,2>(sr,si);
    // ZXZ layer 2
    t = rc[12]; rz_lane<2>(sr,si,t.x,t.y,q);
    t = rc[13]; rx_lane<2>(sr,si,t.x,t.y);
    t = rc[14]; rz_lane<2>(sr,si,t.x,t.y,q);
    t = rc[15]; rz_lane<1>(sr,si,t.x,t.y,q);
    t = rc[16]; rx_lane<1>(sr,si,t.x,t.y);
    t = rc[17]; rz_lane<1>(sr,si,t.x,t.y,q);
    t = rc[18]; rz_reg<2>(sr,si,t.x,t.y);
    t = rc[19]; rx_reg<2>(sr,si,t.x,t.y);
    t = rc[20]; rz_reg<2>(sr,si,t.x,t.y);
    t = rc[21]; rz_reg<1>(sr,si,t.x,t.y);
    t = rc[22]; rx_reg<1>(sr,si,t.x,t.y);
    t = rc[23]; rz_reg<1>(sr,si,t.x,t.y);
}

// RX embedding on all 4 wires (angle d on wire d)
__device__ __forceinline__ void embed4(float sr[4], float si[4],
        float c0, float s0, float c1, float s1,
        float c2, float s2, float c3, float s3) {
    rx_lane<2>(sr,si,c0,s0);
    rx_lane<1>(sr,si,c1,s1);
    rx_reg<2>(sr,si,c2,s2);
    rx_reg<1>(sr,si,c3,s3);
}

__global__ __launch_bounds__(64) void qa_fused(
        const float* __restrict__ x1, const float* __restrict__ x2,
        const float* __restrict__ W, const float* __restrict__ b,
        const float* __restrict__ wq_rot, const float* __restrict__ wq_crx,
        const float* __restrict__ wk_rot, const float* __restrict__ wk_crx,
        const float* __restrict__ wv_rot, const float* __restrict__ wv_crx,
        float* __restrict__ out, int B) {
    // ---- per-block sincos table in LDS:
    // [0,24) wq_rot | [24,28) wq_crx | [28,52) wk_rot | [52,56) wk_crx
    // [56,80) wv_rot | [80,84) wv_crx     (pairs: cos(t/2), sin(t/2))
    __shared__ float2 s_cs[84];
    for (int j = threadIdx.x; j < 84; j += 64) {
        float ang;
        if (j < 24)      ang = wq_rot[j];
        else if (j < 28) ang = wq_crx[j-24];
        else if (j < 52) ang = wk_rot[j-28];
        else if (j < 56) ang = wk_crx[j-52];
        else if (j < 80) ang = wv_rot[j-56];
        else             ang = wv_crx[j-80];
        float h = 0.5f * ang;
        s_cs[j] = make_float2(__cosf(h), __sinf(h));
    }
    __syncthreads();

    int lane = threadIdx.x;
    int q = lane & 3;                       // quad index = wires 0,1
    int e = blockIdx.x * 16 + (lane >> 2);  // batch element
    if (e >= B) return;

    // ---- static K-side constants (per-quad redundant; ~400 instr)
    float kr[4], ki[4];
    kr[0] = (q == 0) ? 1.f : 0.f; kr[1] = kr[2] = kr[3] = 0.f;
    ki[0] = ki[1] = ki[2] = ki[3] = 0.f;
    init_qkv4(kr, ki, s_cs + 28, s_cs + 52, q);
    float pk0 = kr[0]*kr[0]+ki[0]*ki[0], pk1 = kr[1]*kr[1]+ki[1]*ki[1];
    float pk2 = kr[2]*kr[2]+ki[2]*ki[2], pk3 = kr[3]*kr[3]+ki[3]*ki[3];
    float Pk = pk0 + pk1 + pk2 + pk3;
    float cZ4 = qred((q & 2) ? -Pk : Pk);                 // Zphi(w4) = local wire0
    float cZ1 = qred((q & 1) ? -Pk : Pk);                 // Zphi(w5) = wire1
    float cZ2 = qred(pk0 + pk1 - pk2 - pk3);              // Zphi(w6) = wire2
    float cZ3 = qred(pk0 - pk1 + pk2 - pk3);              // Zphi(w7) = wire3
    float cx1 = 0.f;
#pragma unroll
    for (int r = 0; r < 4; ++r) {
        cx1 += kr[r]*__shfl_xor(kr[r],1) + ki[r]*__shfl_xor(ki[r],1);
    }
    float cx2 = 2.f*(kr[0]*kr[2]+ki[0]*ki[2] + kr[1]*kr[3]+ki[1]*ki[3]);
    float cx3 = 2.f*(kr[0]*kr[1]+ki[0]*ki[1] + kr[2]*kr[3]+ki[2]*ki[3]);
    float cX1 = qred(cx1);                                // Xphi(w5) = wire1
    float cX2 = qred(cx2);                                // Xphi(w6) = wire2
    float cX3 = qred(cx3);                                // Xphi(w7) = wire3

    // ---- pre-net: lanes split the 96 inputs; full quad butterfly on all 4
    // accumulators (every lane ends with all 4 complete dot products), then
    // lane q keeps d=q. (R3 bug: selecting before reducing summed the diagonal.)
    float a1[4] = {0,0,0,0}, a2[4] = {0,0,0,0};
    const float4* r1 = (const float4*)(x1 + (size_t)e * 96) + 6*q;
    const float4* r2 = (const float4*)(x2 + (size_t)e * 96) + 6*q;
#pragma unroll
    for (int j = 0; j < 6; ++j) {
        float4 v1 = r1[j], v2 = r2[j];
#pragma unroll
        for (int d = 0; d < 4; ++d) {
            float4 w = *((const float4*)(W + d*96 + 24*q) + j);
            a1[d] = fmaf(v1.x,w.x, fmaf(v1.y,w.y, fmaf(v1.z,w.z, fmaf(v1.w,w.w, a1[d]))));
            a2[d] = fmaf(v2.x,w.x, fmaf(v2.y,w.y, fmaf(v2.z,w.z, fmaf(v2.w,w.w, a2[d]))));
        }
    }
#pragma unroll
    for (int m = 1; m < 4; m <<= 1) {
#pragma unroll
        for (int d = 0; d < 4; ++d) {
            a1[d] += __shfl_xor(a1[d], m);
            a2[d] += __shfl_xor(a2[d], m);
        }
    }
    float s1 = q==0 ? a1[0] : q==1 ? a1[1] : q==2 ? a1[2] : a1[3];
    float s2 = q==0 ? a2[0] : q==1 ? a2[1] : q==2 ? a2[2] : a2[3];
    float xq = s1 + b[q];
    float xk = s2 + b[q];
    float hq = 0.5f*xq, hk = 0.5f*xk;
    float cqq = __cosf(hq), sqq = __sinf(hq);
    float ckq = __cosf(hk), skq = __sinf(hk);
    float cq0 = __shfl(cqq,0,4), cq1 = __shfl(cqq,1,4), cq2 = __shfl(cqq,2,4), cq3 = __shfl(cqq,3,4);
    float sq0 = __shfl(sqq,0,4), sq1 = __shfl(sqq,1,4), sq2 = __shfl(sqq,2,4), sq3 = __shfl(sqq,3,4);
    float ck0 = __shfl(ckq,0,4), ck1 = __shfl(ckq,1,4), ck2 = __shfl(ckq,2,4), ck3 = __shfl(ckq,3,4);
    float sk0 = __shfl(skq,0,4), sk1 = __shfl(skq,1,4), sk2 = __shfl(skq,2,4), sk3 = __shfl(skq,3,4);

    // ---- psi = RX(x2p) . Qinit . RX(x1p) |0000>
    float sr[4], si[4];
    sr[0] = (q == 0) ? 1.f : 0.f; sr[1] = sr[2] = sr[3] = 0.f;
    si[0] = si[1] = si[2] = si[3] = 0.f;
    embed4(sr,si, cq0,sq0, cq1,sq1, cq2,sq2, cq3,sq3);
    init_qkv4(sr,si, s_cs + 0, s_cs + 24, q);
    embed4(sr,si, ck0,sk0, ck1,sk1, ck2,sk2, ck3,sk3);

    // ---- psi observables
    float p0 = sr[0]*sr[0]+si[0]*si[0], p1 = sr[1]*sr[1]+si[1]*si[1];
    float p2 = sr[2]*sr[2]+si[2]*si[2], p3 = sr[3]*sr[3]+si[3]*si[3];
    float P = p0 + p1 + p2 + p3;
    float zw0 = qred((q & 2) ? -P : P);                   // Zpsi(wire0)
    float xw0p = 0.f, xw1p = 0.f;
#pragma unroll
    for (int r = 0; r < 4; ++r) {
        xw0p += sr[r]*__shfl_xor(sr[r],2) + si[r]*__shfl_xor(si[r],2);
        xw1p += sr[r]*__shfl_xor(sr[r],1) + si[r]*__shfl_xor(si[r],1);
    }
    float xw0 = qred(xw0p);                               // Xpsi(wire0)
    float xw1 = qred(xw1p);                               // Xpsi(wire1)
    float xw2 = qred(2.f*(sr[0]*sr[2]+si[0]*si[2] + sr[1]*sr[3]+si[1]*si[3]));
    float xw3 = qred(2.f*(sr[0]*sr[1]+si[0]*si[1] + sr[2]*sr[3]+si[2]*si[3]));

    // ---- factorized score -> mags -> value-embed angles
    float X1 = xw1*cX1, X2 = xw2*cX2, X3 = xw3*cX3, Z4 = zw0*cZ4;
    float mag0 = sqrtf(fmaf(cZ1, cZ1, X1*X1));
    float mag1 = sqrtf(fmaf(cZ2, cZ2, X2*X2));
    float mag2 = sqrtf(fmaf(cZ3, cZ3, X3*X3));
    float mag3 = sqrtf(fmaf(Z4, Z4, xw0*xw0));
    float m = q==0 ? mag0 : q==1 ? mag1 : q==2 ? mag2 : mag3;
    float e2 = __expf(2.f*m);
    float th = (e2 - 1.f) / (e2 + 1.f);                   // tanh(m), m >= 0
    float hv = 0.5f * PI_F * th;
    float cvq = __cosf(hv), svq = __sinf(hv);
    float cv0 = __shfl(cvq,0,4), cv1 = __shfl(cvq,1,4), cv2 = __shfl(cvq,2,4), cv3 = __shfl(cvq,3,4);
    float sv0 = __shfl(svq,0,4), sv1 = __shfl(svq,1,4), sv2 = __shfl(svq,2,4), sv3 = __shfl(svq,3,4);

    // ---- value circuit
    sr[0] = (q == 0) ? 1.f : 0.f; sr[1] = sr[2] = sr[3] = 0.f;
    si[0] = si[1] = si[2] = si[3] = 0.f;
    embed4(sr,si, ck0,sk0, ck1,sk1, ck2,sk2, ck3,sk3);    // RX(xv), xv = x2p
    init_qkv4(sr,si, s_cs + 56, s_cs + 80, q);
    embed4(sr,si, cv0,sv0, cv1,sv1, cv2,sv2, cv3,sv3);    // RX(tanh(mag)*pi)
    cnot_ll<2,1>(sr,si,q);
    cnot_lr<1,2>(sr,si,q);
    cnot_rr<2,1>(sr,si);
    cnot_rl<1,2>(sr,si);

    // ---- output observables Z(w0..3), X(w0..3)
    p0 = sr[0]*sr[0]+si[0]*si[0]; p1 = sr[1]*sr[1]+si[1]*si[1];
    p2 = sr[2]*sr[2]+si[2]*si[2]; p3 = sr[3]*sr[3]+si[3]*si[3];
    float Pv = p0 + p1 + p2 + p3;
    float zo0 = qred((q & 2) ? -Pv : Pv);
    float zo1 = qred((q & 1) ? -Pv : Pv);
    float zo2 = qred(p0 + p1 - p2 - p3);
    float zo3 = qred(p0 - p1 + p2 - p3);
    float xo0p = 0.f, xo1p = 0.f;
#pragma unroll
    for (int r = 0; r < 4; ++r) {
        xo0p += sr[r]*__shfl_xor(sr[r],2) + si[r]*__shfl_xor(si[r],2);
        xo1p += sr[r]*__shfl_xor(sr[r],1) + si[r]*__shfl_xor(si[r],1);
    }
    float xo0 = qred(xo0p);
    float xo1 = qred(xo1p);
    float xo2 = qred(2.f*(sr[0]*sr[2]+si[0]*si[2] + sr[1]*sr[3]+si[1]*si[3]));
    float xo3 = qred(2.f*(sr[0]*sr[1]+si[0]*si[1] + sr[2]*sr[3]+si[2]*si[3]));

    if (q == 0) {
        float4* o4 = (float4*)(out + (size_t)e * 8);
        o4[0] = make_float4(zo0, zo1, zo2, zo3);
        o4[1] = make_float4(xo0, xo1, xo2, xo3);
    }
}

extern "C" void kernel_launch(void* const* d_in, const int* in_sizes, int n_in,
                              void* d_out, int out_size, void* d_ws, size_t ws_size,
                              hipStream_t stream) {
    const float* x1     = (const float*)d_in[0];
    const float* x2     = (const float*)d_in[1];
    const float* W      = (const float*)d_in[2];
    const float* b      = (const float*)d_in[3];
    const float* wq_rot = (const float*)d_in[4];
    const float* wq_crx = (const float*)d_in[5];
    const float* wk_rot = (const float*)d_in[6];
    const float* wk_crx = (const float*)d_in[7];
    const float* wv_rot = (const float*)d_in[8];
    const float* wv_crx = (const float*)d_in[9];
    float* out = (float*)d_out;
    int B = in_sizes[0] / 96;

    int blocks = (B + 15) / 16;   // 16 elements per 64-thread block (4 lanes/elem)
    qa_fused<<<blocks, 64, 0, stream>>>(x1, x2, W, b,
                                        wq_rot, wq_crx, wk_rot, wk_crx,
                                        wv_rot, wv_crx, out, B);
}

// Round 5
// 11.702 us; speedup vs baseline: 4.9900x; 1.1911x over previous
//
#include <hip/hip_runtime.h>
#include <math.h>

#define PI_F 3.14159265358979323846f

// ---------------------------------------------------------------------------
// Fused single-kernel quantum attention.
// 4 lanes per batch element. 4-qubit state (16 amps) split:
//   wires 0,1 -> lane-quad bits (q = lane&3: bit1 = wire0, bit0 = wire1)
//   wires 2,3 -> register index  (r: bit1 = wire2, bit0 = wire3)
// Each lane holds sr[4]/si[4] (4 complex amps). ALL cross-lane traffic is
// intra-quad -> lowered to DPP quad_perm (VALU pipe, no DS latency).
// No module-scope device state; per-block LDS table; one __syncthreads.
// ---------------------------------------------------------------------------

// DPP quad_perm ctrl values
#define DPP_XOR1 0xB1  // [1,0,3,2]
#define DPP_XOR2 0x4E  // [2,3,0,1]
#define DPP_BC0  0x00  // [0,0,0,0]
#define DPP_BC1  0x55  // [1,1,1,1]
#define DPP_BC2  0xAA  // [2,2,2,2]
#define DPP_BC3  0xFF  // [3,3,3,3]

template<int CTRL>
__device__ __forceinline__ float dppf(float x) {
    return __int_as_float(__builtin_amdgcn_update_dpp(
        0, __float_as_int(x), CTRL, 0xF, 0xF, true));
}

template<int L>  // L in {1,2}
__device__ __forceinline__ float qsx(float x) {
    if constexpr (L == 1) return dppf<DPP_XOR1>(x);
    else                  return dppf<DPP_XOR2>(x);
}

__device__ __forceinline__ float qred(float v) {
    v += dppf<DPP_XOR1>(v);
    v += dppf<DPP_XOR2>(v);
    return v;
}

// ---- register-wire gates (wire2 -> M=2, wire3 -> M=1) ----------------------

template<int M>
__device__ __forceinline__ void rz_reg(float sr[4], float si[4], float c, float s) {
#pragma unroll
    for (int r = 0; r < 4; ++r) {
        float d = (r & M) ? s : -s;
        float re = sr[r], im = si[r];
        sr[r] = c*re - d*im;
        si[r] = c*im + d*re;
    }
}

template<int M>
__device__ __forceinline__ void rx_reg(float sr[4], float si[4], float c, float s) {
#pragma unroll
    for (int r0 = 0; r0 < 4; ++r0) {
        if (r0 & M) continue;
        int r1 = r0 | M;
        float a0r = sr[r0], a0i = si[r0], a1r = sr[r1], a1i = si[r1];
        sr[r0] = fmaf(s, a1i, c*a0r);
        si[r0] = fmaf(-s, a1r, c*a0i);
        sr[r1] = fmaf(s, a0i, c*a1r);
        si[r1] = fmaf(-s, a0r, c*a1i);
    }
}

template<int CM, int TM>
__device__ __forceinline__ void crx_rr(float sr[4], float si[4], float c, float s) {
#pragma unroll
    for (int r0 = 0; r0 < 4; ++r0) {
        if ((r0 & CM) == 0 || (r0 & TM)) continue;
        int r1 = r0 | TM;
        float a0r = sr[r0], a0i = si[r0], a1r = sr[r1], a1i = si[r1];
        sr[r0] = fmaf(s, a1i, c*a0r);
        si[r0] = fmaf(-s, a1r, c*a0i);
        sr[r1] = fmaf(s, a0i, c*a1r);
        si[r1] = fmaf(-s, a0r, c*a1i);
    }
}

template<int CM, int TM>
__device__ __forceinline__ void cnot_rr(float sr[4], float si[4]) {
#pragma unroll
    for (int r0 = 0; r0 < 4; ++r0) {
        if ((r0 & CM) == 0 || (r0 & TM)) continue;
        int r1 = r0 | TM;
        float t;
        t = sr[r0]; sr[r0] = sr[r1]; sr[r1] = t;
        t = si[r0]; si[r0] = si[r1]; si[r1] = t;
    }
}

// ---- lane-wire gates (wire0 -> L=2, wire1 -> L=1) ---------------------------

template<int L>
__device__ __forceinline__ void rz_lane(float sr[4], float si[4], float c, float s, int q) {
    float d = (q & L) ? s : -s;
#pragma unroll
    for (int r = 0; r < 4; ++r) {
        float re = sr[r], im = si[r];
        sr[r] = c*re - d*im;
        si[r] = c*im + d*re;
    }
}

template<int L>
__device__ __forceinline__ void rx_lane(float sr[4], float si[4], float c, float s) {
#pragma unroll
    for (int r = 0; r < 4; ++r) {
        float pr = qsx<L>(sr[r]);
        float pi = qsx<L>(si[r]);
        sr[r] = fmaf(s, pi, c*sr[r]);
        si[r] = fmaf(-s, pr, c*si[r]);
    }
}

template<int CL, int TL>
__device__ __forceinline__ void crx_ll(float sr[4], float si[4], float c, float s, int q) {
    bool ctl = (q & CL) != 0;
#pragma unroll
    for (int r = 0; r < 4; ++r) {
        float pr = qsx<TL>(sr[r]);
        float pi = qsx<TL>(si[r]);
        float nr = fmaf(s, pi, c*sr[r]);
        float ni = fmaf(-s, pr, c*si[r]);
        sr[r] = ctl ? nr : sr[r];
        si[r] = ctl ? ni : si[r];
    }
}

template<int CL, int TM>
__device__ __forceinline__ void crx_lr(float sr[4], float si[4], float c, float s, int q) {
    bool ctl = (q & CL) != 0;
#pragma unroll
    for (int r0 = 0; r0 < 4; ++r0) {
        if (r0 & TM) continue;
        int r1 = r0 | TM;
        float a0r = sr[r0], a0i = si[r0], a1r = sr[r1], a1i = si[r1];
        float n0r = fmaf(s, a1i, c*a0r), n0i = fmaf(-s, a1r, c*a0i);
        float n1r = fmaf(s, a0i, c*a1r), n1i = fmaf(-s, a0r, c*a1i);
        sr[r0] = ctl ? n0r : a0r;  si[r0] = ctl ? n0i : a0i;
        sr[r1] = ctl ? n1r : a1r;  si[r1] = ctl ? n1i : a1i;
    }
}

template<int CM, int TL>
__device__ __forceinline__ void crx_rl(float sr[4], float si[4], float c, float s) {
#pragma unroll
    for (int r = 0; r < 4; ++r) {
        if (!(r & CM)) continue;
        float pr = qsx<TL>(sr[r]);
        float pi = qsx<TL>(si[r]);
        sr[r] = fmaf(s, pi, c*sr[r]);
        si[r] = fmaf(-s, pr, c*si[r]);
    }
}

template<int CL, int TL>
__device__ __forceinline__ void cnot_ll(float sr[4], float si[4], int q) {
    bool ctl = (q & CL) != 0;
#pragma unroll
    for (int r = 0; r < 4; ++r) {
        float pr = qsx<TL>(sr[r]);
        float pi = qsx<TL>(si[r]);
        sr[r] = ctl ? pr : sr[r];
        si[r] = ctl ? pi : si[r];
    }
}

template<int CL, int TM>
__device__ __forceinline__ void cnot_lr(float sr[4], float si[4], int q) {
    bool ctl = (q & CL) != 0;
#pragma unroll
    for (int r0 = 0; r0 < 4; ++r0) {
        if (r0 & TM) continue;
        int r1 = r0 | TM;
        float a = sr[r0], b2 = sr[r1];
        sr[r0] = ctl ? b2 : a;  sr[r1] = ctl ? a : b2;
        float ai = si[r0], bi = si[r1];
        si[r0] = ctl ? bi : ai; si[r1] = ctl ? ai : bi;
    }
}

template<int CM, int TL>
__device__ __forceinline__ void cnot_rl(float sr[4], float si[4]) {
#pragma unroll
    for (int r = 0; r < 4; ++r) {
        if (!(r & CM)) continue;
        sr[r] = qsx<TL>(sr[r]);
        si[r] = qsx<TL>(si[r]);
    }
}

// ---- full init_qkv block on wires 0..3 (lane2, lane1, reg2, reg1) -----------
__device__ __forceinline__ void init_qkv4(float sr[4], float si[4],
        const float2* rc, const float2* cc, int q) {
    float2 t;
    // ZXZ layer 1
    t = rc[0];  rz_lane<2>(sr,si,t.x,t.y,q);
    t = rc[1];  rx_lane<2>(sr,si,t.x,t.y);
    t = rc[2];  rz_lane<2>(sr,si,t.x,t.y,q);
    t = rc[3];  rz_lane<1>(sr,si,t.x,t.y,q);
    t = rc[4];  rx_lane<1>(sr,si,t.x,t.y);
    t = rc[5];  rz_lane<1>(sr,si,t.x,t.y,q);
    t = rc[6];  rz_reg<2>(sr,si,t.x,t.y);
    t = rc[7];  rx_reg<2>(sr,si,t.x,t.y);
    t = rc[8];  rz_reg<2>(sr,si,t.x,t.y);
    t = rc[9];  rz_reg<1>(sr,si,t.x,t.y);
    t = rc[10]; rx_reg<1>(sr,si,t.x,t.y);
    t = rc[11]; rz_reg<1>(sr,si,t.x,t.y);
    // CRX ring (0,1),(1,2),(2,3),(3,0)
    t = cc[0];  crx_ll<2,1>(sr,si,t.x,t.y,q);
    t = cc[1];  crx_lr<1,2>(sr,si,t.x,t.y,q);
    t = cc[2];  crx_rr<2,1>(sr,si,t.x,t.y);
    t = cc[3];  crx_rl<1,2>(sr,si,t.x,t.y);
    // CNOTs (0,1),(1,2),(2,3),(3,0),(0,3),(1,0),(2,1),(3,2)
    cnot_ll<2,1>(sr,si,q);
    cnot_lr<1,2>(sr,si,q);
    cnot_rr<2,1>(sr,si);
    cnot_rl<1,2>(sr,si);
    cnot_lr<2,1>(sr,si,q);
    cnot_ll<1,2>(sr,si,q);
    cnot_rl<2,1>(sr,si);
    cnot_rr<1,2>(sr,si);
    // ZXZ layer 2
    t = rc[12]; rz_lane<2>(sr,si,t.x,t.y,q);
    t = rc[13]; rx_lane<2>(sr,si,t.x,t.y);
    t = rc[14]; rz_lane<2>(sr,si,t.x,t.y,q);
    t = rc[15]; rz_lane<1>(sr,si,t.x,t.y,q);
    t = rc[16]; rx_lane<1>(sr,si,t.x,t.y);
    t = rc[17]; rz_lane<1>(sr,si,t.x,t.y,q);
    t = rc[18]; rz_reg<2>(sr,si,t.x,t.y);
    t = rc[19]; rx_reg<2>(sr,si,t.x,t.y);
    t = rc[20]; rz_reg<2>(sr,si,t.x,t.y);
    t = rc[21]; rz_reg<1>(sr,si,t.x,t.y);
    t = rc[22]; rx_reg<1>(sr,si,t.x,t.y);
    t = rc[23]; rz_reg<1>(sr,si,t.x,t.y);
}

// RX embedding on all 4 wires (angle d on wire d)
__device__ __forceinline__ void embed4(float sr[4], float si[4],
        float c0, float s0, float c1, float s1,
        float c2, float s2, float c3, float s3) {
    rx_lane<2>(sr,si,c0,s0);
    rx_lane<1>(sr,si,c1,s1);
    rx_reg<2>(sr,si,c2,s2);
    rx_reg<1>(sr,si,c3,s3);
}

__global__ __launch_bounds__(64) void qa_fused(
        const float* __restrict__ x1, const float* __restrict__ x2,
        const float* __restrict__ W, const float* __restrict__ b,
        const float* __restrict__ wq_rot, const float* __restrict__ wq_crx,
        const float* __restrict__ wk_rot, const float* __restrict__ wk_crx,
        const float* __restrict__ wv_rot, const float* __restrict__ wv_crx,
        float* __restrict__ out, int B) {
    // ---- per-block sincos table in LDS:
    // [0,24) wq_rot | [24,28) wq_crx | [28,52) wk_rot | [52,56) wk_crx
    // [56,80) wv_rot | [80,84) wv_crx     (pairs: cos(t/2), sin(t/2))
    __shared__ float2 s_cs[84];
    for (int j = threadIdx.x; j < 84; j += 64) {
        float ang;
        if (j < 24)      ang = wq_rot[j];
        else if (j < 28) ang = wq_crx[j-24];
        else if (j < 52) ang = wk_rot[j-28];
        else if (j < 56) ang = wk_crx[j-52];
        else if (j < 80) ang = wv_rot[j-56];
        else             ang = wv_crx[j-80];
        float h = 0.5f * ang;
        s_cs[j] = make_float2(__cosf(h), __sinf(h));
    }
    __syncthreads();

    int lane = threadIdx.x;
    int q = lane & 3;                       // quad index = wires 0,1
    int e = blockIdx.x * 16 + (lane >> 2);  // batch element
    if (e >= B) return;

    // ---- static K-side constants (per-quad redundant)
    float kr[4], ki[4];
    kr[0] = (q == 0) ? 1.f : 0.f; kr[1] = kr[2] = kr[3] = 0.f;
    ki[0] = ki[1] = ki[2] = ki[3] = 0.f;
    init_qkv4(kr, ki, s_cs + 28, s_cs + 52, q);
    float pk0 = kr[0]*kr[0]+ki[0]*ki[0], pk1 = kr[1]*kr[1]+ki[1]*ki[1];
    float pk2 = kr[2]*kr[2]+ki[2]*ki[2], pk3 = kr[3]*kr[3]+ki[3]*ki[3];
    float Pk = pk0 + pk1 + pk2 + pk3;
    float cZ4 = qred((q & 2) ? -Pk : Pk);                 // Zphi(w4) = local wire0
    float cZ1 = qred((q & 1) ? -Pk : Pk);                 // Zphi(w5) = wire1
    float cZ2 = qred(pk0 + pk1 - pk2 - pk3);              // Zphi(w6) = wire2
    float cZ3 = qred(pk0 - pk1 + pk2 - pk3);              // Zphi(w7) = wire3
    float cx1 = 0.f;
#pragma unroll
    for (int r = 0; r < 4; ++r) {
        cx1 += kr[r]*qsx<1>(kr[r]) + ki[r]*qsx<1>(ki[r]);
    }
    float cx2 = 2.f*(kr[0]*kr[2]+ki[0]*ki[2] + kr[1]*kr[3]+ki[1]*ki[3]);
    float cx3 = 2.f*(kr[0]*kr[1]+ki[0]*ki[1] + kr[2]*kr[3]+ki[2]*ki[3]);
    float cX1 = qred(cx1);                                // Xphi(w5) = wire1
    float cX2 = qred(cx2);                                // Xphi(w6) = wire2
    float cX3 = qred(cx3);                                // Xphi(w7) = wire3

    // ---- pre-net: lanes split the 96 inputs; full quad butterfly on all 4
    // accumulators (every lane ends with all 4 complete dot products), then
    // lane q keeps d=q.
    float a1[4] = {0,0,0,0}, a2[4] = {0,0,0,0};
    const float4* r1 = (const float4*)(x1 + (size_t)e * 96) + 6*q;
    const float4* r2 = (const float4*)(x2 + (size_t)e * 96) + 6*q;
#pragma unroll
    for (int j = 0; j < 6; ++j) {
        float4 v1 = r1[j], v2 = r2[j];
#pragma unroll
        for (int d = 0; d < 4; ++d) {
            float4 w = *((const float4*)(W + d*96 + 24*q) + j);
            a1[d] = fmaf(v1.x,w.x, fmaf(v1.y,w.y, fmaf(v1.z,w.z, fmaf(v1.w,w.w, a1[d]))));
            a2[d] = fmaf(v2.x,w.x, fmaf(v2.y,w.y, fmaf(v2.z,w.z, fmaf(v2.w,w.w, a2[d]))));
        }
    }
#pragma unroll
    for (int d = 0; d < 4; ++d) {
        a1[d] += dppf<DPP_XOR1>(a1[d]);
        a1[d] += dppf<DPP_XOR2>(a1[d]);
        a2[d] += dppf<DPP_XOR1>(a2[d]);
        a2[d] += dppf<DPP_XOR2>(a2[d]);
    }
    float s1 = q==0 ? a1[0] : q==1 ? a1[1] : q==2 ? a1[2] : a1[3];
    float s2 = q==0 ? a2[0] : q==1 ? a2[1] : q==2 ? a2[2] : a2[3];
    float xq = s1 + b[q];
    float xk = s2 + b[q];
    float hq = 0.5f*xq, hk = 0.5f*xk;
    float cqq = __cosf(hq), sqq = __sinf(hq);
    float ckq = __cosf(hk), skq = __sinf(hk);
    float cq0 = dppf<DPP_BC0>(cqq), cq1 = dppf<DPP_BC1>(cqq), cq2 = dppf<DPP_BC2>(cqq), cq3 = dppf<DPP_BC3>(cqq);
    float sq0 = dppf<DPP_BC0>(sqq), sq1 = dppf<DPP_BC1>(sqq), sq2 = dppf<DPP_BC2>(sqq), sq3 = dppf<DPP_BC3>(sqq);
    float ck0 = dppf<DPP_BC0>(ckq), ck1 = dppf<DPP_BC1>(ckq), ck2 = dppf<DPP_BC2>(ckq), ck3 = dppf<DPP_BC3>(ckq);
    float sk0 = dppf<DPP_BC0>(skq), sk1 = dppf<DPP_BC1>(skq), sk2 = dppf<DPP_BC2>(skq), sk3 = dppf<DPP_BC3>(skq);

    // ---- psi = RX(x2p) . Qinit . RX(x1p) |0000>
    float sr[4], si[4];
    sr[0] = (q == 0) ? 1.f : 0.f; sr[1] = sr[2] = sr[3] = 0.f;
    si[0] = si[1] = si[2] = si[3] = 0.f;
    embed4(sr,si, cq0,sq0, cq1,sq1, cq2,sq2, cq3,sq3);
    init_qkv4(sr,si, s_cs + 0, s_cs + 24, q);
    embed4(sr,si, ck0,sk0, ck1,sk1, ck2,sk2, ck3,sk3);

    // ---- psi observables
    float p0 = sr[0]*sr[0]+si[0]*si[0], p1 = sr[1]*sr[1]+si[1]*si[1];
    float p2 = sr[2]*sr[2]+si[2]*si[2], p3 = sr[3]*sr[3]+si[3]*si[3];
    float P = p0 + p1 + p2 + p3;
    float zw0 = qred((q & 2) ? -P : P);                   // Zpsi(wire0)
    float xw0p = 0.f, xw1p = 0.f;
#pragma unroll
    for (int r = 0; r < 4; ++r) {
        xw0p += sr[r]*qsx<2>(sr[r]) + si[r]*qsx<2>(si[r]);
        xw1p += sr[r]*qsx<1>(sr[r]) + si[r]*qsx<1>(si[r]);
    }
    float xw0 = qred(xw0p);                               // Xpsi(wire0)
    float xw1 = qred(xw1p);                               // Xpsi(wire1)
    float xw2 = qred(2.f*(sr[0]*sr[2]+si[0]*si[2] + sr[1]*sr[3]+si[1]*si[3]));
    float xw3 = qred(2.f*(sr[0]*sr[1]+si[0]*si[1] + sr[2]*sr[3]+si[2]*si[3]));

    // ---- factorized score -> mags -> value-embed angles
    float X1 = xw1*cX1, X2 = xw2*cX2, X3 = xw3*cX3, Z4 = zw0*cZ4;
    float mag0 = sqrtf(fmaf(cZ1, cZ1, X1*X1));
    float mag1 = sqrtf(fmaf(cZ2, cZ2, X2*X2));
    float mag2 = sqrtf(fmaf(cZ3, cZ3, X3*X3));
    float mag3 = sqrtf(fmaf(Z4, Z4, xw0*xw0));
    float m = q==0 ? mag0 : q==1 ? mag1 : q==2 ? mag2 : mag3;
    float e2 = __expf(2.f*m);
    float th = (e2 - 1.f) / (e2 + 1.f);                   // tanh(m), m >= 0
    float hv = 0.5f * PI_F * th;
    float cvq = __cosf(hv), svq = __sinf(hv);
    float cv0 = dppf<DPP_BC0>(cvq), cv1 = dppf<DPP_BC1>(cvq), cv2 = dppf<DPP_BC2>(cvq), cv3 = dppf<DPP_BC3>(cvq);
    float sv0 = dppf<DPP_BC0>(svq), sv1 = dppf<DPP_BC1>(svq), sv2 = dppf<DPP_BC2>(svq), sv3 = dppf<DPP_BC3>(svq);

    // ---- value circuit
    sr[0] = (q == 0) ? 1.f : 0.f; sr[1] = sr[2] = sr[3] = 0.f;
    si[0] = si[1] = si[2] = si[3] = 0.f;
    embed4(sr,si, ck0,sk0, ck1,sk1, ck2,sk2, ck3,sk3);    // RX(xv), xv = x2p
    init_qkv4(sr,si, s_cs + 56, s_cs + 80, q);
    embed4(sr,si, cv0,sv0, cv1,sv1, cv2,sv2, cv3,sv3);    // RX(tanh(mag)*pi)
    cnot_ll<2,1>(sr,si,q);
    cnot_lr<1,2>(sr,si,q);
    cnot_rr<2,1>(sr,si);
    cnot_rl<1,2>(sr,si);

    // ---- output observables Z(w0..3), X(w0..3)
    p0 = sr[0]*sr[0]+si[0]*si[0]; p1 = sr[1]*sr[1]+si[1]*si[1];
    p2 = sr[2]*sr[2]+si[2]*si[2]; p3 = sr[3]*sr[3]+si[3]*si[3];
    float Pv = p0 + p1 + p2 + p3;
    float zo0 = qred((q & 2) ? -Pv : Pv);
    float zo1 = qred((q & 1) ? -Pv : Pv);
    float zo2 = qred(p0 + p1 - p2 - p3);
    float zo3 = qred(p0 - p1 + p2 - p3);
    float xo0p = 0.f, xo1p = 0.f;
#pragma unroll
    for (int r = 0; r < 4; ++r) {
        xo0p += sr[r]*qsx<2>(sr[r]) + si[r]*qsx<2>(si[r]);
        xo1p += sr[r]*qsx<1>(sr[r]) + si[r]*qsx<1>(si[r]);
    }
    float xo0 = qred(xo0p);
    float xo1 = qred(xo1p);
    float xo2 = qred(2.f*(sr[0]*sr[2]+si[0]*si[2] + sr[1]*sr[3]+si[1]*si[3]));
    float xo3 = qred(2.f*(sr[0]*sr[1]+si[0]*si[1] + sr[2]*sr[3]+si[2]*si[3]));

    if (q == 0) {
        float4* o4 = (float4*)(out + (size_t)e * 8);
        o4[0] = make_float4(zo0, zo1, zo2, zo3);
        o4[1] = make_float4(xo0, xo1, xo2, xo3);
    }
}

extern "C" void kernel_launch(void* const* d_in, const int* in_sizes, int n_in,
                              void* d_out, int out_size, void* d_ws, size_t ws_size,
                              hipStream_t stream) {
    const float* x1     = (const float*)d_in[0];
    const float* x2     = (const float*)d_in[1];
    const float* W      = (const float*)d_in[2];
    const float* b      = (const float*)d_in[3];
    const float* wq_rot = (const float*)d_in[4];
    const float* wq_crx = (const float*)d_in[5];
    const float* wk_rot = (const float*)d_in[6];
    const float* wk_crx = (const float*)d_in[7];
    const float* wv_rot = (const float*)d_in[8];
    const float* wv_crx = (const float*)d_in[9];
    float* out = (float*)d_out;
    int B = in_sizes[0] / 96;

    int blocks = (B + 15) / 16;   // 16 elements per 64-thread block (4 lanes/elem)
    qa_fused<<<blocks, 64, 0, stream>>>(x1, x2, W, b,
                                        wq_rot, wq_crx, wk_rot, wk_crx,
                                        wv_rot, wv_crx, out, B);
}

// Round 6
// 11.146 us; speedup vs baseline: 5.2388x; 1.0499x over previous
//
#include <hip/hip_runtime.h>
#include <math.h>

#define PI_F 3.14159265358979323846f
typedef unsigned int uint;

// ---------------------------------------------------------------------------
// 16 lanes per batch element; 1 complex amp per lane (ar, ai).
// Amp index = lane&15 with wire0->bit8, wire1->bit4, wire2->bit2, wire3->bit1.
// All cross-lane ops are DPP (VALU pipe): xor1/xor2 quad_perm, xor8 row_ror:8,
// xor4 = row_half_mirror (xor7) then quad_perm xor3.
// Static ZXZ triples pre-fused into SU(2) [[a,b],[-b*,a*]] in an LDS table.
// K-side constants computed once per block by group 0. 256 thr/block = 16 elems.
// ---------------------------------------------------------------------------

template<int CTRL>
__device__ __forceinline__ float dppf(float x) {
    return __int_as_float(__builtin_amdgcn_update_dpp(
        0, __float_as_int(x), CTRL, 0xF, 0xF, true));
}

// xor-shuffle across lane-bit W within each 16-lane row
template<int W>
__device__ __forceinline__ float shx(float x) {
    if constexpr (W == 1) return dppf<0xB1>(x);                    // quad xor1
    else if constexpr (W == 2) return dppf<0x4E>(x);               // quad xor2
    else if constexpr (W == 4) return dppf<0x1B>(dppf<0x141>(x));  // xor7∘xor3
    else return dppf<0x128>(x);                                    // row_ror:8
}

__device__ __forceinline__ float xorf(float x, uint u) {
    return __int_as_float(__float_as_int(x) ^ u);
}

// sum over the 16-lane row (result uniform in row)
__device__ __forceinline__ float red16(float v) {
    v += dppf<0xB1>(v);
    v += dppf<0x4E>(v);   // now quad-uniform
    v += dppf<0x141>(v);  // xor7 == xor4 on quad-uniform values
    v += dppf<0x128>(v);  // other half
    return v;
}

// SU(2) [[alpha,beta],[-beta*,alpha*]] on wire with lane-mask W.
// g = (a_r, a_i, b_r, b_i); sgn = per-lane signbit mask for this wire.
template<int W>
__device__ __forceinline__ void su2g(float &ar, float &ai, float4 g, uint sgn) {
    float Ai = xorf(g.y, sgn);   // bit1 lanes use conj(alpha)
    float Br = xorf(g.z, sgn);   // bit1 lanes use -beta*
    float pr = shx<W>(ar), pi = shx<W>(ai);
    float nr = g.x*ar - Ai*ai + Br*pr - g.w*pi;
    float ni = g.x*ai + Ai*ar + Br*pi + g.w*pr;
    ar = nr; ai = ni;
}

// RX: new = c*a - i s*partner (lane-symmetric)
template<int W>
__device__ __forceinline__ void rxg(float &ar, float &ai, float c, float s) {
    float pr = shx<W>(ar), pi = shx<W>(ai);
    float nr = fmaf(s, pi, c*ar);
    float ni = fmaf(-s, pr, c*ai);
    ar = nr; ai = ni;
}

template<int C, int W>
__device__ __forceinline__ void crxg(float &ar, float &ai, float2 cs, int lane) {
    bool ctl = (lane & C) != 0;
    float ec = ctl ? cs.x : 1.0f;
    float es = ctl ? cs.y : 0.0f;
    float pr = shx<W>(ar), pi = shx<W>(ai);
    float nr = fmaf(es, pi, ec*ar);
    float ni = fmaf(-es, pr, ec*ai);
    ar = nr; ai = ni;
}

template<int C, int W>
__device__ __forceinline__ void cnotg(float &ar, float &ai, int lane) {
    float pr = shx<W>(ar), pi = shx<W>(ai);
    bool ctl = (lane & C) != 0;
    ar = ctl ? pr : ar;
    ai = ctl ? pi : ai;
}

// full init_qkv: 4 SU2 + CRX ring + 8 CNOT + 4 SU2
__device__ __forceinline__ void init16(float &ar, float &ai,
        const float4* su, const float2* cx, int lane,
        uint s8, uint s4, uint s2, uint s1) {
    su2g<8>(ar, ai, su[0], s8);
    su2g<4>(ar, ai, su[1], s4);
    su2g<2>(ar, ai, su[2], s2);
    su2g<1>(ar, ai, su[3], s1);
    crxg<8,4>(ar, ai, cx[0], lane);
    crxg<4,2>(ar, ai, cx[1], lane);
    crxg<2,1>(ar, ai, cx[2], lane);
    crxg<1,8>(ar, ai, cx[3], lane);
    cnotg<8,4>(ar, ai, lane);
    cnotg<4,2>(ar, ai, lane);
    cnotg<2,1>(ar, ai, lane);
    cnotg<1,8>(ar, ai, lane);
    cnotg<8,1>(ar, ai, lane);
    cnotg<4,8>(ar, ai, lane);
    cnotg<2,4>(ar, ai, lane);
    cnotg<1,2>(ar, ai, lane);
    su2g<8>(ar, ai, su[4], s8);
    su2g<4>(ar, ai, su[5], s4);
    su2g<2>(ar, ai, su[6], s2);
    su2g<1>(ar, ai, su[7], s1);
}

__global__ __launch_bounds__(256) void qa_fused(
        const float* __restrict__ x1, const float* __restrict__ x2,
        const float* __restrict__ W, const float* __restrict__ b,
        const float* __restrict__ wq_rot, const float* __restrict__ wq_crx,
        const float* __restrict__ wk_rot, const float* __restrict__ wk_crx,
        const float* __restrict__ wv_rot, const float* __restrict__ wv_crx,
        float* __restrict__ out, int B) {
    __shared__ float4 s_su[24];  // [init*8 + gate], init 0=Q,1=K,2=V
    __shared__ float2 s_cx[12];  // [init*4 + idx]
    __shared__ float  s_kc[8];   // cZ1,cZ2,cZ3,cZ4,cX1,cX2,cX3

    int t = threadIdx.x;
    // ---- static tables: fuse each ZXZ triple into SU(2); CRX sincos
    if (t < 36) {
        if (t < 24) {
            int ini = t >> 3, g = t & 7;
            const float* rp = (ini == 0) ? wq_rot : (ini == 1) ? wk_rot : wv_rot;
            int base = (g & 4) ? 12 + 3*(g & 3) : 3*(g & 3);
            float t0 = rp[base], t1 = rp[base+1], t2 = rp[base+2];
            float hp = 0.5f*(t0+t2), hm = 0.5f*(t0-t2), h1 = 0.5f*t1;
            float cp = __cosf(hp), sp = __sinf(hp);
            float cm = __cosf(hm), sm = __sinf(hm);
            float c1 = __cosf(h1), s1v = __sinf(h1);
            // alpha = c1*e^{-i(t0+t2)/2}, beta = -i*s1*e^{i(t0-t2)/2}
            s_su[t] = make_float4(c1*cp, -c1*sp, s1v*sm, -s1v*cm);
        } else {
            int j = t - 24;
            int ini = j >> 2, idx = j & 3;
            const float* cp = (ini == 0) ? wq_crx : (ini == 1) ? wk_crx : wv_crx;
            float a = cp[idx] * 0.5f;
            s_cx[j] = make_float2(__cosf(a), __sinf(a));
        }
    }
    __syncthreads();

    int lane = t & 15;
    uint s8 = (lane & 8) ? 0x80000000u : 0u;
    uint s4 = (lane & 4) ? 0x80000000u : 0u;
    uint s2 = (lane & 2) ? 0x80000000u : 0u;
    uint s1 = (lane & 1) ? 0x80000000u : 0u;

    // ---- static K-side constants, once per block (group 0 only)
    if (t < 16) {
        float kr = (lane == 0) ? 1.f : 0.f, ki = 0.f;
        init16(kr, ki, s_su + 8, s_cx + 4, lane, s8, s4, s2, s1);
        float p = kr*kr + ki*ki;
        float cZ1 = red16(xorf(p, s4));   // Zphi(w5) = local wire1
        float cZ2 = red16(xorf(p, s2));   // Zphi(w6)
        float cZ3 = red16(xorf(p, s1));   // Zphi(w7)
        float cZ4 = red16(xorf(p, s8));   // Zphi(w4)
        float cX1 = red16(kr*shx<4>(kr) + ki*shx<4>(ki));  // Xphi(w5)
        float cX2 = red16(kr*shx<2>(kr) + ki*shx<2>(ki));  // Xphi(w6)
        float cX3 = red16(kr*shx<1>(kr) + ki*shx<1>(ki));  // Xphi(w7)
        if (lane == 0) {
            s_kc[0]=cZ1; s_kc[1]=cZ2; s_kc[2]=cZ3; s_kc[3]=cZ4;
            s_kc[4]=cX1; s_kc[5]=cX2; s_kc[6]=cX3;
        }
    }
    __syncthreads();

    int e = blockIdx.x * 16 + (t >> 4);
    if (e >= B) return;

    // ---- pre-net: coalesced lane-split dot products, 16-lane reduce
    float a10=0,a11=0,a12=0,a13=0, a20=0,a21=0,a22=0,a23=0;
    const float* x1r = x1 + (size_t)e*96 + lane;
    const float* x2r = x2 + (size_t)e*96 + lane;
#pragma unroll
    for (int j = 0; j < 6; ++j) {
        float v1 = x1r[16*j], v2 = x2r[16*j];
        float w0 = W[0*96 + 16*j + lane];
        float w1 = W[1*96 + 16*j + lane];
        float w2 = W[2*96 + 16*j + lane];
        float w3 = W[3*96 + 16*j + lane];
        a10 = fmaf(v1,w0,a10); a11 = fmaf(v1,w1,a11);
        a12 = fmaf(v1,w2,a12); a13 = fmaf(v1,w3,a13);
        a20 = fmaf(v2,w0,a20); a21 = fmaf(v2,w1,a21);
        a22 = fmaf(v2,w2,a22); a23 = fmaf(v2,w3,a23);
    }
    a10 = red16(a10); a11 = red16(a11); a12 = red16(a12); a13 = red16(a13);
    a20 = red16(a20); a21 = red16(a21); a22 = red16(a22); a23 = red16(a23);
    float bx = b[0], by = b[1], bz = b[2], bw = b[3];
    float hq0 = 0.5f*(a10+bx), hq1 = 0.5f*(a11+by), hq2 = 0.5f*(a12+bz), hq3 = 0.5f*(a13+bw);
    float hk0 = 0.5f*(a20+bx), hk1 = 0.5f*(a21+by), hk2 = 0.5f*(a22+bz), hk3 = 0.5f*(a23+bw);
    float cq0 = __cosf(hq0), sq0 = __sinf(hq0);
    float cq1 = __cosf(hq1), sq1 = __sinf(hq1);
    float cq2 = __cosf(hq2), sq2 = __sinf(hq2);
    float cq3 = __cosf(hq3), sq3 = __sinf(hq3);
    float ck0 = __cosf(hk0), sk0 = __sinf(hk0);
    float ck1 = __cosf(hk1), sk1 = __sinf(hk1);
    float ck2 = __cosf(hk2), sk2 = __sinf(hk2);
    float ck3 = __cosf(hk3), sk3 = __sinf(hk3);

    // ---- psi = RX(x2p) . Qinit . RX(x1p) |0000>
    float ar = (lane == 0) ? 1.f : 0.f, ai = 0.f;
    rxg<8>(ar,ai,cq0,sq0);
    rxg<4>(ar,ai,cq1,sq1);
    rxg<2>(ar,ai,cq2,sq2);
    rxg<1>(ar,ai,cq3,sq3);
    init16(ar, ai, s_su + 0, s_cx + 0, lane, s8, s4, s2, s1);
    rxg<8>(ar,ai,ck0,sk0);
    rxg<4>(ar,ai,ck1,sk1);
    rxg<2>(ar,ai,ck2,sk2);
    rxg<1>(ar,ai,ck3,sk3);

    // ---- score observables (factorized across the product state)
    float p = ar*ar + ai*ai;
    float zw0 = red16(xorf(p, s8));
    float xw0 = red16(ar*shx<8>(ar) + ai*shx<8>(ai));
    float xw1 = red16(ar*shx<4>(ar) + ai*shx<4>(ai));
    float xw2 = red16(ar*shx<2>(ar) + ai*shx<2>(ai));
    float xw3 = red16(ar*shx<1>(ar) + ai*shx<1>(ai));

    float cZ1 = s_kc[0], cZ2 = s_kc[1], cZ3 = s_kc[2], cZ4 = s_kc[3];
    float cX1 = s_kc[4], cX2 = s_kc[5], cX3 = s_kc[6];
    float X1 = xw1*cX1, X2 = xw2*cX2, X3 = xw3*cX3, Z4 = zw0*cZ4;
    float mag0 = sqrtf(fmaf(cZ1,cZ1,X1*X1));
    float mag1 = sqrtf(fmaf(cZ2,cZ2,X2*X2));
    float mag2 = sqrtf(fmaf(cZ3,cZ3,X3*X3));
    float mag3 = sqrtf(fmaf(Z4,Z4,xw0*xw0));
    // tanh(m)*pi/2, m >= 0
    float e20 = __expf(2.f*mag0), e21 = __expf(2.f*mag1);
    float e22 = __expf(2.f*mag2), e23 = __expf(2.f*mag3);
    float hv0 = 0.5f*PI_F*(e20-1.f)/(e20+1.f);
    float hv1 = 0.5f*PI_F*(e21-1.f)/(e21+1.f);
    float hv2 = 0.5f*PI_F*(e22-1.f)/(e22+1.f);
    float hv3 = 0.5f*PI_F*(e23-1.f)/(e23+1.f);
    float cv0 = __cosf(hv0), sv0 = __sinf(hv0);
    float cv1 = __cosf(hv1), sv1 = __sinf(hv1);
    float cv2 = __cosf(hv2), sv2 = __sinf(hv2);
    float cv3 = __cosf(hv3), sv3 = __sinf(hv3);

    // ---- value circuit
    ar = (lane == 0) ? 1.f : 0.f; ai = 0.f;
    rxg<8>(ar,ai,ck0,sk0);
    rxg<4>(ar,ai,ck1,sk1);
    rxg<2>(ar,ai,ck2,sk2);
    rxg<1>(ar,ai,ck3,sk3);
    init16(ar, ai, s_su + 16, s_cx + 8, lane, s8, s4, s2, s1);
    rxg<8>(ar,ai,cv0,sv0);
    rxg<4>(ar,ai,cv1,sv1);
    rxg<2>(ar,ai,cv2,sv2);
    rxg<1>(ar,ai,cv3,sv3);
    cnotg<8,4>(ar, ai, lane);
    cnotg<4,2>(ar, ai, lane);
    cnotg<2,1>(ar, ai, lane);
    cnotg<1,8>(ar, ai, lane);

    // ---- output observables Z(w0..3), X(w0..3)
    p = ar*ar + ai*ai;
    float zo0 = red16(xorf(p, s8));
    float zo1 = red16(xorf(p, s4));
    float zo2 = red16(xorf(p, s2));
    float zo3 = red16(xorf(p, s1));
    float xo0 = red16(ar*shx<8>(ar) + ai*shx<8>(ai));
    float xo1 = red16(ar*shx<4>(ar) + ai*shx<4>(ai));
    float xo2 = red16(ar*shx<2>(ar) + ai*shx<2>(ai));
    float xo3 = red16(ar*shx<1>(ar) + ai*shx<1>(ai));

    if (lane == 0) {
        float4* o4 = (float4*)(out + (size_t)e * 8);
        o4[0] = make_float4(zo0, zo1, zo2, zo3);
        o4[1] = make_float4(xo0, xo1, xo2, xo3);
    }
}

extern "C" void kernel_launch(void* const* d_in, const int* in_sizes, int n_in,
                              void* d_out, int out_size, void* d_ws, size_t ws_size,
                              hipStream_t stream) {
    const float* x1     = (const float*)d_in[0];
    const float* x2     = (const float*)d_in[1];
    const float* W      = (const float*)d_in[2];
    const float* b      = (const float*)d_in[3];
    const float* wq_rot = (const float*)d_in[4];
    const float* wq_crx = (const float*)d_in[5];
    const float* wk_rot = (const float*)d_in[6];
    const float* wk_crx = (const float*)d_in[7];
    const float* wv_rot = (const float*)d_in[8];
    const float* wv_crx = (const float*)d_in[9];
    float* out = (float*)d_out;
    int B = in_sizes[0] / 96;

    int blocks = (B + 15) / 16;   // 16 elements per 256-thread block (16 lanes/elem)
    qa_fused<<<blocks, 256, 0, stream>>>(x1, x2, W, b,
                                         wq_rot, wq_crx, wk_rot, wk_crx,
                                         wv_rot, wv_crx, out, B);
}

// Round 7
// 11.076 us; speedup vs baseline: 5.2719x; 1.0063x over previous
//
#include <hip/hip_runtime.h>
#include <math.h>

#define PI_F 3.14159265358979323846f
typedef unsigned int uint;

// ---------------------------------------------------------------------------
// 16 lanes per element-pair; 2 batch elements per lane (dual ILP chains).
// Amp index = lane&15: wire0->bit8, wire1->bit4, wire2->bit2, wire3->bit1.
// All cross-lane ops are DPP (VALU pipe). Static ZXZ triples pre-fused into
// SU(2) [[a,b],[-b*,a*]] in LDS. K-side constants computed per 16-lane group
// in-stream (no second barrier). 64-thr blocks (1 wave), 8 elems/block.
// ---------------------------------------------------------------------------

template<int CTRL>
__device__ __forceinline__ float dppf(float x) {
    return __int_as_float(__builtin_amdgcn_update_dpp(
        0, __float_as_int(x), CTRL, 0xF, 0xF, true));
}

// xor-shuffle across lane-bit W within each 16-lane row
template<int W>
__device__ __forceinline__ float shx(float x) {
    if constexpr (W == 1) return dppf<0xB1>(x);                    // quad xor1
    else if constexpr (W == 2) return dppf<0x4E>(x);               // quad xor2
    else if constexpr (W == 4) return dppf<0x1B>(dppf<0x141>(x));  // xor7∘xor3
    else return dppf<0x128>(x);                                    // row_ror:8
}

__device__ __forceinline__ float xorf(float x, uint u) {
    return __int_as_float(__float_as_int(x) ^ u);
}

// sum over the 16-lane row (result uniform in row)
__device__ __forceinline__ float red16(float v) {
    v += dppf<0xB1>(v);
    v += dppf<0x4E>(v);   // quad-uniform
    v += dppf<0x141>(v);  // xor7 == xor4 on quad-uniform
    v += dppf<0x128>(v);  // other half
    return v;
}

// SU(2) [[alpha,beta],[-beta*,alpha*]] on wire mask W; N independent chains
template<int W, int N>
__device__ __forceinline__ void su2g(float (&ar)[N], float (&ai)[N], float4 g, uint sgn) {
    float Ai = xorf(g.y, sgn);
    float Br = xorf(g.z, sgn);
#pragma unroll
    for (int el = 0; el < N; ++el) {
        float pr = shx<W>(ar[el]), pi = shx<W>(ai[el]);
        float nr = g.x*ar[el] - Ai*ai[el] + Br*pr - g.w*pi;
        float ni = g.x*ai[el] + Ai*ar[el] + Br*pi + g.w*pr;
        ar[el] = nr; ai[el] = ni;
    }
}

// RX with per-chain (c,s)
template<int W, int N>
__device__ __forceinline__ void rxg(float (&ar)[N], float (&ai)[N],
                                    const float (&c)[N], const float (&s)[N]) {
#pragma unroll
    for (int el = 0; el < N; ++el) {
        float pr = shx<W>(ar[el]), pi = shx<W>(ai[el]);
        float nr = fmaf(s[el], pi, c[el]*ar[el]);
        float ni = fmaf(-s[el], pr, c[el]*ai[el]);
        ar[el] = nr; ai[el] = ni;
    }
}

template<int C, int W, int N>
__device__ __forceinline__ void crxg(float (&ar)[N], float (&ai)[N], float2 cs, int lane) {
    bool ctl = (lane & C) != 0;
    float ec = ctl ? cs.x : 1.0f;
    float es = ctl ? cs.y : 0.0f;
#pragma unroll
    for (int el = 0; el < N; ++el) {
        float pr = shx<W>(ar[el]), pi = shx<W>(ai[el]);
        float nr = fmaf(es, pi, ec*ar[el]);
        float ni = fmaf(-es, pr, ec*ai[el]);
        ar[el] = nr; ai[el] = ni;
    }
}

template<int C, int W, int N>
__device__ __forceinline__ void cnotg(float (&ar)[N], float (&ai)[N], int lane) {
    bool ctl = (lane & C) != 0;
#pragma unroll
    for (int el = 0; el < N; ++el) {
        float pr = shx<W>(ar[el]), pi = shx<W>(ai[el]);
        ar[el] = ctl ? pr : ar[el];
        ai[el] = ctl ? pi : ai[el];
    }
}

// full init_qkv: 4 SU2 + CRX ring + 8 CNOT + 4 SU2
template<int N>
__device__ __forceinline__ void init16(float (&ar)[N], float (&ai)[N],
        const float4* su, const float2* cx, int lane,
        uint s8, uint s4, uint s2, uint s1) {
    su2g<8>(ar, ai, su[0], s8);
    su2g<4>(ar, ai, su[1], s4);
    su2g<2>(ar, ai, su[2], s2);
    su2g<1>(ar, ai, su[3], s1);
    crxg<8,4>(ar, ai, cx[0], lane);
    crxg<4,2>(ar, ai, cx[1], lane);
    crxg<2,1>(ar, ai, cx[2], lane);
    crxg<1,8>(ar, ai, cx[3], lane);
    cnotg<8,4>(ar, ai, lane);
    cnotg<4,2>(ar, ai, lane);
    cnotg<2,1>(ar, ai, lane);
    cnotg<1,8>(ar, ai, lane);
    cnotg<8,1>(ar, ai, lane);
    cnotg<4,8>(ar, ai, lane);
    cnotg<2,4>(ar, ai, lane);
    cnotg<1,2>(ar, ai, lane);
    su2g<8>(ar, ai, su[4], s8);
    su2g<4>(ar, ai, su[5], s4);
    su2g<2>(ar, ai, su[6], s2);
    su2g<1>(ar, ai, su[7], s1);
}

__global__ __launch_bounds__(64) void qa_fused(
        const float* __restrict__ x1, const float* __restrict__ x2,
        const float* __restrict__ Wp, const float* __restrict__ b,
        const float* __restrict__ wq_rot, const float* __restrict__ wq_crx,
        const float* __restrict__ wk_rot, const float* __restrict__ wk_crx,
        const float* __restrict__ wv_rot, const float* __restrict__ wv_crx,
        float* __restrict__ out, int B) {
    __shared__ float4 s_su[24];  // [init*8 + gate], init 0=Q,1=K,2=V
    __shared__ float2 s_cx[12];  // [init*4 + idx]

    int t = threadIdx.x;
    // ---- static tables: fuse each ZXZ triple into SU(2); CRX sincos
    if (t < 36) {
        if (t < 24) {
            int ini = t >> 3, g = t & 7;
            const float* rp = (ini == 0) ? wq_rot : (ini == 1) ? wk_rot : wv_rot;
            int base = (g & 4) ? 12 + 3*(g & 3) : 3*(g & 3);
            float t0 = rp[base], t1 = rp[base+1], t2 = rp[base+2];
            float hp = 0.5f*(t0+t2), hm = 0.5f*(t0-t2), h1 = 0.5f*t1;
            float cp = __cosf(hp), sp = __sinf(hp);
            float cm = __cosf(hm), sm = __sinf(hm);
            float c1 = __cosf(h1), s1v = __sinf(h1);
            // alpha = c1*e^{-i(t0+t2)/2}, beta = -i*s1*e^{i(t0-t2)/2}
            s_su[t] = make_float4(c1*cp, -c1*sp, s1v*sm, -s1v*cm);
        } else {
            int j = t - 24;
            int ini = j >> 2, idx = j & 3;
            const float* cp = (ini == 0) ? wq_crx : (ini == 1) ? wk_crx : wv_crx;
            float a = cp[idx] * 0.5f;
            s_cx[j] = make_float2(__cosf(a), __sinf(a));
        }
    }
    __syncthreads();

    int lane = t & 15;
    int grp  = t >> 4;                       // 0..3
    uint s8 = (lane & 8) ? 0x80000000u : 0u;
    uint s4 = (lane & 4) ? 0x80000000u : 0u;
    uint s2 = (lane & 2) ? 0x80000000u : 0u;
    uint s1 = (lane & 1) ? 0x80000000u : 0u;

    int e0 = blockIdx.x * 8 + 2*grp;
    if (e0 >= B) return;
    int e1 = (e0 + 1 < B) ? e0 + 1 : B - 1;

    // ---- static K-side constants, per group, in-stream (no extra barrier)
    float kc[7];
    {
        float kr[1], ki[1];
        kr[0] = (lane == 0) ? 1.f : 0.f; ki[0] = 0.f;
        init16(kr, ki, s_su + 8, s_cx + 4, lane, s8, s4, s2, s1);
        float p = kr[0]*kr[0] + ki[0]*ki[0];
        kc[0] = red16(xorf(p, s4));   // cZ1 = Zphi(w5)
        kc[1] = red16(xorf(p, s2));   // cZ2 = Zphi(w6)
        kc[2] = red16(xorf(p, s1));   // cZ3 = Zphi(w7)
        kc[3] = red16(xorf(p, s8));   // cZ4 = Zphi(w4)
        kc[4] = red16(fmaf(kr[0], shx<4>(kr[0]), ki[0]*shx<4>(ki[0])));  // cX1
        kc[5] = red16(fmaf(kr[0], shx<2>(kr[0]), ki[0]*shx<2>(ki[0])));  // cX2
        kc[6] = red16(fmaf(kr[0], shx<1>(kr[0]), ki[0]*shx<1>(ki[0])));  // cX3
    }

    // ---- pre-net for both elements (shared W loads)
    float A1[2][4] = {{0,0,0,0},{0,0,0,0}};
    float A2[2][4] = {{0,0,0,0},{0,0,0,0}};
    const float* xp1[2] = { x1 + (size_t)e0*96 + lane, x1 + (size_t)e1*96 + lane };
    const float* xp2[2] = { x2 + (size_t)e0*96 + lane, x2 + (size_t)e1*96 + lane };
#pragma unroll
    for (int j = 0; j < 6; ++j) {
        float w[4];
#pragma unroll
        for (int d = 0; d < 4; ++d) w[d] = Wp[d*96 + 16*j + lane];
#pragma unroll
        for (int el = 0; el < 2; ++el) {
            float v1 = xp1[el][16*j], v2 = xp2[el][16*j];
#pragma unroll
            for (int d = 0; d < 4; ++d) {
                A1[el][d] = fmaf(v1, w[d], A1[el][d]);
                A2[el][d] = fmaf(v2, w[d], A2[el][d]);
            }
        }
    }
    float Bv[4] = { b[0], b[1], b[2], b[3] };
    float CQ[4][2], SQ[4][2], CK[4][2], SK[4][2];
#pragma unroll
    for (int el = 0; el < 2; ++el) {
#pragma unroll
        for (int d = 0; d < 4; ++d) {
            float hq = 0.5f*(red16(A1[el][d]) + Bv[d]);
            float hk = 0.5f*(red16(A2[el][d]) + Bv[d]);
            CQ[d][el] = __cosf(hq); SQ[d][el] = __sinf(hq);
            CK[d][el] = __cosf(hk); SK[d][el] = __sinf(hk);
        }
    }

    // ---- psi = RX(x2p) . Qinit . RX(x1p) |0000>  (dual chains)
    float ar[2], ai[2];
    ar[0] = (lane == 0) ? 1.f : 0.f; ar[1] = ar[0];
    ai[0] = 0.f; ai[1] = 0.f;
    rxg<8>(ar, ai, CQ[0], SQ[0]);
    rxg<4>(ar, ai, CQ[1], SQ[1]);
    rxg<2>(ar, ai, CQ[2], SQ[2]);
    rxg<1>(ar, ai, CQ[3], SQ[3]);
    init16(ar, ai, s_su + 0, s_cx + 0, lane, s8, s4, s2, s1);
    rxg<8>(ar, ai, CK[0], SK[0]);
    rxg<4>(ar, ai, CK[1], SK[1]);
    rxg<2>(ar, ai, CK[2], SK[2]);
    rxg<1>(ar, ai, CK[3], SK[3]);

    // ---- score observables -> mags -> value-embed angles
    float CV[4][2], SV[4][2];
#pragma unroll
    for (int el = 0; el < 2; ++el) {
        float p = ar[el]*ar[el] + ai[el]*ai[el];
        float zw0 = red16(xorf(p, s8));
        float xw0 = red16(fmaf(ar[el], shx<8>(ar[el]), ai[el]*shx<8>(ai[el])));
        float xw1 = red16(fmaf(ar[el], shx<4>(ar[el]), ai[el]*shx<4>(ai[el])));
        float xw2 = red16(fmaf(ar[el], shx<2>(ar[el]), ai[el]*shx<2>(ai[el])));
        float xw3 = red16(fmaf(ar[el], shx<1>(ar[el]), ai[el]*shx<1>(ai[el])));
        float X1 = xw1*kc[4], X2 = xw2*kc[5], X3 = xw3*kc[6], Z4 = zw0*kc[3];
        float mg[4];
        mg[0] = sqrtf(fmaf(kc[0], kc[0], X1*X1));
        mg[1] = sqrtf(fmaf(kc[1], kc[1], X2*X2));
        mg[2] = sqrtf(fmaf(kc[2], kc[2], X3*X3));
        mg[3] = sqrtf(fmaf(Z4, Z4, xw0*xw0));
#pragma unroll
        for (int d = 0; d < 4; ++d) {
            float e2 = __expf(2.f*mg[d]);
            float hv = 0.5f*PI_F*(e2 - 1.f)/(e2 + 1.f);   // tanh(m)*pi/2
            CV[d][el] = __cosf(hv); SV[d][el] = __sinf(hv);
        }
    }

    // ---- value circuit (dual chains)
    ar[0] = (lane == 0) ? 1.f : 0.f; ar[1] = ar[0];
    ai[0] = 0.f; ai[1] = 0.f;
    rxg<8>(ar, ai, CK[0], SK[0]);    // RX(xv), xv = x2p
    rxg<4>(ar, ai, CK[1], SK[1]);
    rxg<2>(ar, ai, CK[2], SK[2]);
    rxg<1>(ar, ai, CK[3], SK[3]);
    init16(ar, ai, s_su + 16, s_cx + 8, lane, s8, s4, s2, s1);
    rxg<8>(ar, ai, CV[0], SV[0]);    // RX(tanh(mag)*pi)
    rxg<4>(ar, ai, CV[1], SV[1]);
    rxg<2>(ar, ai, CV[2], SV[2]);
    rxg<1>(ar, ai, CV[3], SV[3]);
    cnotg<8,4>(ar, ai, lane);
    cnotg<4,2>(ar, ai, lane);
    cnotg<2,1>(ar, ai, lane);
    cnotg<1,8>(ar, ai, lane);

    // ---- output observables Z(w0..3), X(w0..3) for both elements
    float ZO[4][2], XO[4][2];
#pragma unroll
    for (int el = 0; el < 2; ++el) {
        float p = ar[el]*ar[el] + ai[el]*ai[el];
        ZO[0][el] = red16(xorf(p, s8));
        ZO[1][el] = red16(xorf(p, s4));
        ZO[2][el] = red16(xorf(p, s2));
        ZO[3][el] = red16(xorf(p, s1));
        XO[0][el] = red16(fmaf(ar[el], shx<8>(ar[el]), ai[el]*shx<8>(ai[el])));
        XO[1][el] = red16(fmaf(ar[el], shx<4>(ar[el]), ai[el]*shx<4>(ai[el])));
        XO[2][el] = red16(fmaf(ar[el], shx<2>(ar[el]), ai[el]*shx<2>(ai[el])));
        XO[3][el] = red16(fmaf(ar[el], shx<1>(ar[el]), ai[el]*shx<1>(ai[el])));
    }

    if (lane == 0) {
        float4* o0 = (float4*)(out + (size_t)e0 * 8);
        o0[0] = make_float4(ZO[0][0], ZO[1][0], ZO[2][0], ZO[3][0]);
        o0[1] = make_float4(XO[0][0], XO[1][0], XO[2][0], XO[3][0]);
        if (e0 + 1 < B) {
            float4* o1 = (float4*)(out + (size_t)(e0 + 1) * 8);
            o1[0] = make_float4(ZO[0][1], ZO[1][1], ZO[2][1], ZO[3][1]);
            o1[1] = make_float4(XO[0][1], XO[1][1], XO[2][1], XO[3][1]);
        }
    }
}

extern "C" void kernel_launch(void* const* d_in, const int* in_sizes, int n_in,
                              void* d_out, int out_size, void* d_ws, size_t ws_size,
                              hipStream_t stream) {
    const float* x1     = (const float*)d_in[0];
    const float* x2     = (const float*)d_in[1];
    const float* W      = (const float*)d_in[2];
    const float* b      = (const float*)d_in[3];
    const float* wq_rot = (const float*)d_in[4];
    const float* wq_crx = (const float*)d_in[5];
    const float* wk_rot = (const float*)d_in[6];
    const float* wk_crx = (const float*)d_in[7];
    const float* wv_rot = (const float*)d_in[8];
    const float* wv_crx = (const float*)d_in[9];
    float* out = (float*)d_out;
    int B = in_sizes[0] / 96;

    int blocks = (B + 7) / 8;   // 8 elements per 64-thread block (2 per lane)
    qa_fused<<<blocks, 64, 0, stream>>>(x1, x2, W, b,
                                        wq_rot, wq_crx, wk_rot, wk_crx,
                                        wv_rot, wv_crx, out, B);
}